// Round 15
// baseline (8891.363 us; speedup 1.0000x reference)
//
#include <hip/hip_runtime.h>

#define SEQ   512
#define NTHR  512
#define NBLK  256
#define XPAD  516

typedef _Float16 f16x8 __attribute__((ext_vector_type(8)));
typedef float    f32x4 __attribute__((ext_vector_type(4)));

#define MFMA(a, b, c) __builtin_amdgcn_mfma_f32_16x16x32_f16((a), (b), (c), 0, 0, 0)
#define AGT __HIP_MEMORY_SCOPE_AGENT

__device__ __forceinline__ float sig_(float x) {
    return __builtin_amdgcn_rcpf(1.0f + __builtin_amdgcn_exp2f(x * -1.4426950408889634f));
}
__device__ __forceinline__ float tanh_(float x) {
    return fmaf(2.0f, __builtin_amdgcn_rcpf(1.0f + __builtin_amdgcn_exp2f(x * -2.8853900817779268f)), -1.0f);
}

// Cross-block layer pipeline: 64 batch-groups x 4 layer-blocks.
// Block (g = bid&63, ell = bid>>6): layer ell, batch rows g*16..g*16+15.
// 8 waves, 2 M-tiles/wave, MFMA N=16 = 16 REAL batch (zero fragment waste).
// Self-h recurrence in LDS (1 barrier/iter). Cross-layer h via d_ws ring
// (R=4 slots, 2KB each) with agent-scope release/acquire flags; consumer
// credit flag gates slot reuse. Replay-safe value handshake (-1 / -2).
__global__ __launch_bounds__(NTHR, 2) void lstm4_grid(
    const float* __restrict__ x,
    const float* __restrict__ W0, const float* __restrict__ B0,
    const float* __restrict__ W1, const float* __restrict__ B1,
    const float* __restrict__ W2, const float* __restrict__ B2,
    const float* __restrict__ W3, const float* __restrict__ B3,
    const float* __restrict__ ln_g, const float* __restrict__ ln_b,
    const float* __restrict__ Wout, const float* __restrict__ bout,
    float* __restrict__ out, void* __restrict__ ws)
{
    __shared__ __align__(16) _Float16 hself[2][16][64];   // 4 KB, [parity][b][k]
    __shared__ float xall[16][XPAD];                      // 33 KB (ell==0)
    __shared__ float part[16][8][16][3];                  // 24 KB (ell==3)
    __shared__ float sconst[2];

    int* const  prodF = (int*)ws;
    int* const  consF = prodF + 512;
    char* const hring = (char*)ws + 4096;

    const int tid  = threadIdx.x;
    const int lane = tid & 63;
    const int w    = tid >> 6;         // wave 0..7
    const int lam  = lane >> 4;        // 0..3 (k-fragment group)
    const int bc   = lane & 15;        // batch column 0..15 (REAL)
    const int g    = blockIdx.x & 63;  // batch group
    const int ell  = blockIdx.x >> 6;  // layer

    const int sidxP = g * 3 + ell;       // produce edge (ell<3)
    const int sidxC = g * 3 + ell - 1;   // consume edge (ell>0)
    char* const        slotP = hring + (long)sidxP * 4 * 2048;
    const char* const  slotC = hring + (long)sidxC * 4 * 2048;

    // ---- replay-safe handshake (tid 0) ----
    if (tid == 0) {
        if (ell < 3) __hip_atomic_store(&prodF[sidxP], -1, __ATOMIC_RELEASE, AGT);
        if (ell > 0) {
            while (__hip_atomic_load(&prodF[sidxC], __ATOMIC_ACQUIRE, AGT) != -1) {}
            __hip_atomic_store(&consF[sidxC], -2, __ATOMIC_RELEASE, AGT);
        }
        if (ell < 3) {
            while (__hip_atomic_load(&consF[sidxP], __ATOMIC_ACQUIRE, AGT) != -2) {}
        }
    }

    // ---- zero self-h (both parities) ----
    for (int i = tid; i < 2 * 16 * 64; i += NTHR)
        ((_Float16*)hself)[i] = (_Float16)0.0f;
    // ---- stage x (layer-0 blocks) ----
    if (ell == 0) {
        for (int i = tid; i < 16 * SEQ; i += NTHR)
            xall[i >> 9][i & 511] = x[(g * 16 + (i >> 9)) * SEQ + (i & 511)];
    }
    if (tid < 64) {
        float a = ln_g[tid] * Wout[tid];
        float b = ln_b[tid] * Wout[tid];
#pragma unroll
        for (int off = 32; off > 0; off >>= 1) {
            a += __shfl_xor(a, off, 64);
            b += __shfl_xor(b, off, 64);
        }
        if (tid == 0) { sconst[0] = a; sconst[1] = b; }
    }

    const float* Wp = (ell == 0) ? W0 : (ell == 1) ? W1 : (ell == 2) ? W2 : W3;
    const float* Bp = (ell == 0) ? B0 : (ell == 1) ? B1 : (ell == 2) ? B2 : B3;

    // ---- weights: 2 tiles/wave, gate-permuted A columns ----
    f16x8 wf[2][4];
    f32x4 biasv[2], wx[2];
    float gw[2];
    int   wrm[2];
#pragma unroll
    for (int i = 0; i < 2; ++i) {
        const int T  = 2 * w + i;
        const int cA = (bc & 3) * 64 + T * 4 + (bc >> 2);  // A-row bc -> (gate, m)
#pragma unroll
        for (int kt = 0; kt < 4; ++kt)
#pragma unroll
            for (int e = 0; e < 8; ++e) wf[i][kt][e] = (_Float16)0.0f;
        if (ell == 0) {
#pragma unroll
            for (int e = 0; e < 8; ++e) {
                wf[i][2][e] = (_Float16)W0[(1 + lam * 8 + e) * 256 + cA];   // self k 0..31
                wf[i][3][e] = (_Float16)W0[(33 + lam * 8 + e) * 256 + cA];  // self k 32..63
            }
#pragma unroll
            for (int r = 0; r < 4; ++r) wx[i][r] = W0[r * 64 + T * 4 + lam]; // x weight
        } else {
#pragma unroll
            for (int kt = 0; kt < 4; ++kt)      // 0,1 = in-h; 2,3 = self-h
#pragma unroll
                for (int e = 0; e < 8; ++e)
                    wf[i][kt][e] = (_Float16)Wp[(kt * 32 + lam * 8 + e) * 256 + cA];
#pragma unroll
            for (int r = 0; r < 4; ++r) wx[i][r] = 0.0f;
        }
#pragma unroll
        for (int r = 0; r < 4; ++r) biasv[i][r] = Bp[r * 64 + T * 4 + lam];
        const int m = T * 4 + lam;
        gw[i]  = ln_g[m] * Wout[m];
        wrm[i] = bc * 128 + (((m >> 3) ^ (bc & 7)) * 16) + (m & 7) * 2;
    }

    // LDS self-frag read offsets (chunk-XOR swizzled), global in-frag offsets
    const int rq0 = bc * 128 + ((lam)     ^ (bc & 7)) * 16;
    const int rq1 = bc * 128 + ((lam + 4) ^ (bc & 7)) * 16;
    const int go0 = bc * 128 + lam * 16, go1 = go0 + 64;

    // publish-wave (w==7) lane constants: unswizzle LDS -> linear global
    const int pr = lane >> 2, pq = (lane & 3) * 2;
    const int lp0 = pr * 128 + ((pq)     ^ (pr & 7)) * 16;
    const int lp1 = pr * 128 + ((pq + 1) ^ (pr & 7)) * 16;
    const int gs0 = pr * 128 + pq * 16, gs1 = gs0 + 16;

    float cst0 = 0.0f, cst1 = 0.0f;
    char* const hb = (char*)hself;

    // ---- prologue prefetch: h_in(0) ----
    f16x8 in0 = {}, in1 = {};
    if (ell > 0) {
        while (__hip_atomic_load(&prodF[sidxC], __ATOMIC_ACQUIRE, AGT) < 0) {}
        in0 = *(const f16x8*)(slotC + go0);
        in1 = *(const f16x8*)(slotC + go1);
    }
    __syncthreads();
    const float Sgw = sconst[0];
    const float Sbw = sconst[1] + bout[0];

    for (int t = 0; t < SEQ; ++t) {
        const int pR = ((t + 1) & 1) * 2048;   // parity holding h(t-1)
        const int pW = (t & 1) * 2048;         // parity for h(t)

        const f16x8 sb0 = *(const f16x8*)(hb + pR + rq0);
        const f16x8 sb1 = *(const f16x8*)(hb + pR + rq1);

        // ---- publish h(t-1) (wave 7, producers) ----
        if (ell < 3 && w == 7 && t >= 1) {
            if (t >= 5)
                while (__hip_atomic_load(&consF[sidxP], __ATOMIC_RELAXED, AGT) < t - 5) {}
            char* gs = slotP + ((t - 1) & 3) * 2048;
            const f16x8 d0 = *(const f16x8*)(hb + pR + lp0);
            const f16x8 d1 = *(const f16x8*)(hb + pR + lp1);
            *(f16x8*)(gs + gs0) = d0;
            *(f16x8*)(gs + gs1) = d1;
            asm volatile("s_waitcnt vmcnt(0)" ::: "memory");
            if (lane == 0)
                __hip_atomic_store(&prodF[sidxP], t - 1, __ATOMIC_RELEASE, AGT);
        }

        // ---- MFMA: 2 tiles, K = in(64) + self(64) ----
        f32x4 A0 = biasv[0], A1 = biasv[1];
        if (ell == 0) {
            const float xv = xall[bc][t];
#pragma unroll
            for (int r = 0; r < 4; ++r) {
                A0[r] = fmaf(xv, wx[0][r], A0[r]);
                A1[r] = fmaf(xv, wx[1][r], A1[r]);
            }
        } else {
            A0 = MFMA(wf[0][0], in0, A0);  A1 = MFMA(wf[1][0], in0, A1);
            A0 = MFMA(wf[0][1], in1, A0);  A1 = MFMA(wf[1][1], in1, A1);
        }
        A0 = MFMA(wf[0][2], sb0, A0);  A1 = MFMA(wf[1][2], sb0, A1);
        A0 = MFMA(wf[0][3], sb1, A0);  A1 = MFMA(wf[1][3], sb1, A1);

        // ---- gates: 2 sets, fully in-lane (C-regs = i,f,g,o of (m, bc)) ----
        const float gi0 = sig_(A0[0]), gf0 = sig_(A0[1]);
        const float gg0 = tanh_(A0[2]), go_0 = sig_(A0[3]);
        cst0 = fmaf(gf0, cst0, gi0 * gg0);
        const float hn0 = go_0 * tanh_(cst0);
        const float gi1 = sig_(A1[0]), gf1 = sig_(A1[1]);
        const float gg1 = tanh_(A1[2]), go_1 = sig_(A1[3]);
        cst1 = fmaf(gf1, cst1, gi1 * gg1);
        const float hn1 = go_1 * tanh_(cst1);
        *(_Float16*)(hb + pW + wrm[0]) = (_Float16)hn0;
        *(_Float16*)(hb + pW + wrm[1]) = (_Float16)hn1;

        // ---- LN partials (layer 3) ----
        if (ell == 3) {
            float v1 = hn0 + hn1;
            float v2 = fmaf(hn0, hn0, hn1 * hn1);
            float v3 = fmaf(hn0, gw[0], hn1 * gw[1]);
            v1 += __shfl_xor(v1, 16, 64); v2 += __shfl_xor(v2, 16, 64); v3 += __shfl_xor(v3, 16, 64);
            v1 += __shfl_xor(v1, 32, 64); v2 += __shfl_xor(v2, 32, 64); v3 += __shfl_xor(v3, 32, 64);
            if (lam == 0) {
                float* pp = &part[t & 15][w][bc][0];
                pp[0] = v1; pp[1] = v2; pp[2] = v3;
            }
        }

        // ---- consumer: credit release + prefetch h_in(t+1) ----
        if (ell > 0) {
            if (tid == 0)
                __hip_atomic_store(&consF[sidxC], t, __ATOMIC_RELEASE, AGT);
            if (t + 1 < SEQ) {
                while (__hip_atomic_load(&prodF[sidxC], __ATOMIC_ACQUIRE, AGT) < t + 1) {}
                const char* sp = slotC + ((t + 1) & 3) * 2048;
                in0 = *(const f16x8*)(sp + go0);
                in1 = *(const f16x8*)(sp + go1);
            }
        }
        __syncthreads();

        // ---- LN combine + out (layer 3, every 8 steps, post-barrier) ----
        if (ell == 3 && (t & 7) == 7) {
            const int slot = (t - 7 + w) & 15;
            const int b    = lane >> 2, ws2 = lane & 3;
            float u1 = part[slot][ws2][b][0] + part[slot][ws2 + 4][b][0];
            float u2 = part[slot][ws2][b][1] + part[slot][ws2 + 4][b][1];
            float u3 = part[slot][ws2][b][2] + part[slot][ws2 + 4][b][2];
            u1 += __shfl_xor(u1, 1, 64); u2 += __shfl_xor(u2, 1, 64); u3 += __shfl_xor(u3, 1, 64);
            u1 += __shfl_xor(u1, 2, 64); u2 += __shfl_xor(u2, 2, 64); u3 += __shfl_xor(u3, 2, 64);
            if (ws2 == 0) {
                const float mu = u1 * (1.0f / 64.0f);
                float var = fmaf(u2, 1.0f / 64.0f, -mu * mu);
                var = fmaxf(var, 0.0f);
                const float rs = rsqrtf(var + 1e-5f);
                out[(g * 16 + b) * SEQ + (t - 7) + w] = fmaf(rs, fmaf(-mu, Sgw, u3), Sbw);
            }
        }
    }

    // ---- epilogue: publish h(511) ----
    if (ell < 3 && w == 7) {
        while (__hip_atomic_load(&consF[sidxP], __ATOMIC_RELAXED, AGT) < 507) {}
        const int pL = (511 & 1) * 2048;
        char* gs = slotP + (511 & 3) * 2048;
        const f16x8 d0 = *(const f16x8*)(hb + pL + lp0);
        const f16x8 d1 = *(const f16x8*)(hb + pL + lp1);
        *(f16x8*)(gs + gs0) = d0;
        *(f16x8*)(gs + gs1) = d1;
        asm volatile("s_waitcnt vmcnt(0)" ::: "memory");
        if (lane == 0)
            __hip_atomic_store(&prodF[sidxP], 511, __ATOMIC_RELEASE, AGT);
    }
}

extern "C" void kernel_launch(void* const* d_in, const int* in_sizes, int n_in,
                              void* d_out, int out_size, void* d_ws, size_t ws_size,
                              hipStream_t stream)
{
    const float* x    = (const float*)d_in[0];
    const float* W0   = (const float*)d_in[1];
    const float* B0   = (const float*)d_in[2];
    const float* W1   = (const float*)d_in[3];
    const float* B1   = (const float*)d_in[4];
    const float* W2   = (const float*)d_in[5];
    const float* B2   = (const float*)d_in[6];
    const float* W3   = (const float*)d_in[7];
    const float* B3   = (const float*)d_in[8];
    const float* ln_g = (const float*)d_in[9];
    const float* ln_b = (const float*)d_in[10];
    const float* Wout = (const float*)d_in[11];
    const float* bout = (const float*)d_in[12];
    float* out = (float*)d_out;

    lstm4_grid<<<NBLK, NTHR, 0, stream>>>(x, W0, B0, W1, B1, W2, B2, W3, B3,
                                          ln_g, ln_b, Wout, bout, out, d_ws);
}

// Round 16
// 649.733 us; speedup vs baseline: 13.6846x; 13.6846x over previous
//
#include <hip/hip_runtime.h>

#define SEQ   512
#define NTHR  1024
#define NBLK  256
#define WGS __HIP_MEMORY_SCOPE_WORKGROUP

typedef _Float16 f16x8 __attribute__((ext_vector_type(8)));
typedef float    f32x4 __attribute__((ext_vector_type(4)));

#define MFMA(a, b, c) __builtin_amdgcn_mfma_f32_16x16x32_f16((a), (b), (c), 0, 0, 0)

__device__ __forceinline__ float sig_(float x) {
    return __builtin_amdgcn_rcpf(1.0f + __builtin_amdgcn_exp2f(x * -1.4426950408889634f));
}
// sign-safe tanh via 2*sigmoid(2x)-1
__device__ __forceinline__ float tanh_(float x) {
    return fmaf(2.0f, __builtin_amdgcn_rcpf(1.0f + __builtin_amdgcn_exp2f(x * -2.8853900817779268f)), -1.0f);
}

// Self-timed layer pipeline, 16 waves: wave w -> layer ell=w>>2, quarter om=w&3
// (4 M-tiles). NO per-tick __syncthreads: per-layer LDS generation counters
// prog[ell] (each wave release-increments after writing its h quarter for step
// t; prog[ell] reaching 4*(t+1) means h_ell(t) complete). Each wave free-runs
// t=0..511 with three acquire-waits:
//   own   : prog[ell]   >= 4t        (self-h(t-1) complete; also own-ring WAR)
//   input : prog[ell-1] >= 4(t+1)    (h_{ell-1}(t) ready)          [ell>0]
//   WAR   : prog[ell+1] >= 4(t-3)    (ring slot t&3 free, 4-deep)  [ell<3, t>=4]
// h ring: [slot=t&3][layer][b][k]. Self-read slot (t-1)&3, input slot t&3.
// Waves of different layers sit on the same SIMD (w&3 mapping) at staggered
// phases -> gate VALU/trans of one wave overlaps MFMA chains of the others.
__global__ __launch_bounds__(NTHR, 4) void lstm4_flow(
    const float* __restrict__ x,
    const float* __restrict__ W0, const float* __restrict__ B0,
    const float* __restrict__ W1, const float* __restrict__ B1,
    const float* __restrict__ W2, const float* __restrict__ B2,
    const float* __restrict__ W3, const float* __restrict__ B3,
    const float* __restrict__ ln_g, const float* __restrict__ ln_b,
    const float* __restrict__ Wout, const float* __restrict__ bout,
    float* __restrict__ out)
{
    __shared__ __align__(16) _Float16 hbuf[4][4][4][64];   // 8 KB [slot][layer][b][k]
    __shared__ float xall[4][SEQ];                         // 8 KB
    __shared__ float part[16][4][4][3];                    // 3 KB [slot16][om][b][c]
    __shared__ float sconst[2];
    __shared__ int   prog[4][16];                          // use [l][0]

    const int tid  = threadIdx.x;
    const int lane = tid & 63;
    const int w    = tid >> 6;        // wave 0..15
    const int ell  = w >> 2;          // layer
    const int om   = w & 3;           // tile quarter
    const int lam  = lane >> 4;
    const int bc   = lane & 15;
    const int br   = bc & 3;
    const int kq   = bc >> 2;         // owned tile within quarter
    const int bb   = blockIdx.x;

    // ---- stage x, zero h (all 4 slots), zero flags ----
    for (int i = tid; i < 4 * SEQ; i += NTHR)
        xall[i >> 9][i & 511] = x[bb * 4 * SEQ + i];
    for (int i = tid; i < 4 * 4 * 4 * 64; i += NTHR)
        ((_Float16*)hbuf)[i] = (_Float16)0.0f;
    if (tid < 4) prog[tid][0] = 0;

    if (tid < 64) {
        float a = ln_g[tid] * Wout[tid];
        float b = ln_b[tid] * Wout[tid];
#pragma unroll
        for (int off = 32; off > 0; off >>= 1) {
            a += __shfl_xor(a, off, 64);
            b += __shfl_xor(b, off, 64);
        }
        if (tid == 0) { sconst[0] = a; sconst[1] = b; }
    }

    const float* Wp = (ell == 0) ? W0 : (ell == 1) ? W1 : (ell == 2) ? W2 : W3;
    const float* Bp = (ell == 0) ? B0 : (ell == 1) ? B1 : (ell == 2) ? B2 : B3;

    // ---- per-wave weights: 4 tiles, gate-permuted cols; biases in VGPR ----
    f16x8 wf[4][4];
    f32x4 biasv[4];
#pragma unroll
    for (int i = 0; i < 4; ++i) {
        const int T  = om * 4 + i;
        const int cA = (bc & 3) * 64 + T * 4 + (bc >> 2);
        if (ell == 0) {
#pragma unroll
            for (int kt = 0; kt < 2; ++kt)          // slots 0,1 = SELF h weights
#pragma unroll
                for (int e = 0; e < 8; ++e)
                    wf[i][kt][e] = (_Float16)W0[(1 + kt * 32 + lam * 8 + e) * 256 + cA];
#pragma unroll
            for (int e = 0; e < 8; ++e) { wf[i][2][e] = (_Float16)0.0f; wf[i][3][e] = (_Float16)0.0f; }
            if (lam == 0) wf[i][2][0] = (_Float16)W0[cA];   // x weight, one-hot A-frag
        } else {
#pragma unroll
            for (int kt = 0; kt < 4; ++kt)          // 0,1 = in-h; 2,3 = self-h
#pragma unroll
                for (int e = 0; e < 8; ++e)
                    wf[i][kt][e] = (_Float16)Wp[(kt * 32 + lam * 8 + e) * 256 + cA];
        }
#pragma unroll
        for (int r = 0; r < 4; ++r)
            biasv[i][r] = Bp[r * 64 + T * 4 + lam];
    }

    const int   mK  = (om * 4 + kq) * 4 + lam;
    const float gwK = ln_g[mK] * Wout[mK];
    const int   wrK = br * 128 + (((mK >> 3) ^ br) * 16) + (mK & 7) * 2;

    const int a0 = br * 128 + ((lam)     ^ br) * 16;
    const int a1 = br * 128 + ((4 + lam) ^ br) * 16;

    const bool k1b = (bc & 4) != 0;
    const bool k2b = (bc & 8) != 0;

    f16x8 xf;
#pragma unroll
    for (int e = 0; e < 8; ++e) xf[e] = (_Float16)0.0f;

    float cstK = 0.0f;
    char* const hb = (char*)hbuf;

    int* const pOwn = &prog[ell][0];
    int* const pIn  = &prog[(ell > 0) ? ell - 1 : 0][0];
    int* const pDn  = &prog[(ell < 3) ? ell + 1 : 3][0];

    __syncthreads();                       // init fence (the only barrier)
    const float Sgw = sconst[0];
    const float Sbw = sconst[1] + bout[0];

    for (int t = 0; t < SEQ; ++t) {
        const int t4 = 4 * t;

        // ---- acquire-waits ----
        while (__hip_atomic_load(pOwn, __ATOMIC_ACQUIRE, WGS) < t4) {}
        if (ell > 0)
            while (__hip_atomic_load(pIn, __ATOMIC_ACQUIRE, WGS) < t4 + 4) {}
        if (ell < 3 && t >= 4)
            while (__hip_atomic_load(pDn, __ATOMIC_ACQUIRE, WGS) < t4 - 12) {}
        __builtin_amdgcn_sched_barrier(0);

        const int sW = ((t & 3) * 4 + ell) * 512;          // write slot
        const int sS = (((t - 1) & 3) * 4 + ell) * 512;    // self slot (t=0 -> 3, zeroed)

        f16x8 b0, b1, b2, b3;
        if (ell == 0) {
            b0 = *(const f16x8*)(hb + sS + a0);
            b1 = *(const f16x8*)(hb + sS + a1);
            if (lam == 0) xf[0] = (_Float16)xall[br][t];
            b2 = xf; b3 = xf;
        } else {
            const int sI = ((t & 3) * 4 + (ell - 1)) * 512;
            b0 = *(const f16x8*)(hb + sI + a0);
            b1 = *(const f16x8*)(hb + sI + a1);
            b2 = *(const f16x8*)(hb + sS + a0);
            b3 = *(const f16x8*)(hb + sS + a1);
        }

        f32x4 A0 = MFMA(wf[0][0], b0, biasv[0]);
        f32x4 A1 = MFMA(wf[1][0], b0, biasv[1]);
        f32x4 A2 = MFMA(wf[2][0], b0, biasv[2]);
        f32x4 A3 = MFMA(wf[3][0], b0, biasv[3]);
        A0 = MFMA(wf[0][1], b1, A0);  A1 = MFMA(wf[1][1], b1, A1);
        A2 = MFMA(wf[2][1], b1, A2);  A3 = MFMA(wf[3][1], b1, A3);
        A0 = MFMA(wf[0][2], b2, A0);  A1 = MFMA(wf[1][2], b2, A1);
        A2 = MFMA(wf[2][2], b2, A2);  A3 = MFMA(wf[3][2], b2, A3);
        A0 = MFMA(wf[0][3], b3, A0);  A1 = MFMA(wf[1][3], b3, A1);
        A2 = MFMA(wf[2][3], b3, A2);  A3 = MFMA(wf[3][3], b3, A3);

        const f32x4 s01 = k1b ? A1 : A0;
        const f32x4 s23 = k1b ? A3 : A2;
        const f32x4 aK  = k2b ? s23 : s01;

        const float gi = sig_(aK[0]);
        const float gf = sig_(aK[1]);
        const float gg = tanh_(aK[2]);
        const float go = sig_(aK[3]);
        cstK = fmaf(gf, cstK, gi * gg);
        const float hn = go * tanh_(cstK);
        *(_Float16*)(hb + sW + wrK) = (_Float16)hn;

        if (ell == 3) {
            float v1 = hn, v2 = hn * hn, v3 = hn * gwK;
            v1 += __shfl_xor(v1, 4, 64);  v2 += __shfl_xor(v2, 4, 64);  v3 += __shfl_xor(v3, 4, 64);
            v1 += __shfl_xor(v1, 8, 64);  v2 += __shfl_xor(v2, 8, 64);  v3 += __shfl_xor(v3, 8, 64);
            v1 += __shfl_xor(v1, 16, 64); v2 += __shfl_xor(v2, 16, 64); v3 += __shfl_xor(v3, 16, 64);
            v1 += __shfl_xor(v1, 32, 64); v2 += __shfl_xor(v2, 32, 64); v3 += __shfl_xor(v3, 32, 64);
            if (bc < 4) {
                float* pp = &part[t & 15][om][bc][0];
                pp[0] = v1; pp[1] = v2; pp[2] = v3;
            }
        }

        // ---- publish step completion (release: h + part writes visible) ----
        if (lane == 0)
            __hip_atomic_fetch_add(pOwn, 1, __ATOMIC_RELEASE, WGS);

        // ---- LN combine + out: layer-3 group only, every 8 steps ----
        if (ell == 3 && (t & 7) == 7) {
            while (__hip_atomic_load(pOwn, __ATOMIC_ACQUIRE, WGS) < t4 + 4) {}
            __builtin_amdgcn_sched_barrier(0);
            const int s  = lane >> 5;          // 2 slots per wave
            const int j  = lane & 31;
            const int b  = (j >> 3) & 3;
            const int o  = j & 3;
            const int ts = t - 7 + 2 * om + s;
            const int sl = ts & 15;
            float u1 = part[sl][o][b][0];
            float u2 = part[sl][o][b][1];
            float u3 = part[sl][o][b][2];
            u1 += __shfl_xor(u1, 1, 64); u2 += __shfl_xor(u2, 1, 64); u3 += __shfl_xor(u3, 1, 64);
            u1 += __shfl_xor(u1, 2, 64); u2 += __shfl_xor(u2, 2, 64); u3 += __shfl_xor(u3, 2, 64);
            if ((j & 7) == 0) {
                const float mu = u1 * (1.0f / 64.0f);
                float var = fmaf(u2, 1.0f / 64.0f, -mu * mu);
                var = fmaxf(var, 0.0f);
                const float rs = rsqrtf(var + 1e-5f);
                out[(bb * 4 + b) * SEQ + ts] = fmaf(rs, fmaf(-mu, Sgw, u3), Sbw);
            }
        }
    }
}

extern "C" void kernel_launch(void* const* d_in, const int* in_sizes, int n_in,
                              void* d_out, int out_size, void* d_ws, size_t ws_size,
                              hipStream_t stream)
{
    const float* x    = (const float*)d_in[0];
    const float* W0   = (const float*)d_in[1];
    const float* B0   = (const float*)d_in[2];
    const float* W1   = (const float*)d_in[3];
    const float* B1   = (const float*)d_in[4];
    const float* W2   = (const float*)d_in[5];
    const float* B2   = (const float*)d_in[6];
    const float* W3   = (const float*)d_in[7];
    const float* B3   = (const float*)d_in[8];
    const float* ln_g = (const float*)d_in[9];
    const float* ln_b = (const float*)d_in[10];
    const float* Wout = (const float*)d_in[11];
    const float* bout = (const float*)d_in[12];
    float* out = (float*)d_out;

    lstm4_flow<<<NBLK, NTHR, 0, stream>>>(x, W0, B0, W1, B1, W2, B2, W3, B3,
                                          ln_g, ln_b, Wout, bout, out);
}

// Round 17
// 549.166 us; speedup vs baseline: 16.1907x; 1.1831x over previous
//
#include <hip/hip_runtime.h>

#define SEQ   512
#define NTHR  1024
#define NBLK  256

typedef _Float16 f16x8 __attribute__((ext_vector_type(8)));
typedef float    f32x4 __attribute__((ext_vector_type(4)));

#define MFMA(a, b, c) __builtin_amdgcn_mfma_f32_16x16x32_f16((a), (b), (c), 0, 0, 0)

__device__ __forceinline__ float sig_(float x) {
    return __builtin_amdgcn_rcpf(1.0f + __builtin_amdgcn_exp2f(x * -1.4426950408889634f));
}
// sign-safe tanh via 2*sigmoid(2x)-1
__device__ __forceinline__ float tanh_(float x) {
    return fmaf(2.0f, __builtin_amdgcn_rcpf(1.0f + __builtin_amdgcn_exp2f(x * -2.8853900817779268f)), -1.0f);
}

// Software-pipelined acc across ticks, skew 2 ticks/layer: at tick tau, wave of
// layer ell FINISHES acc for t=tau-2*ell (self-MFMAs, h_ell(t-1) written last
// tick), STARTS acc for t+1 (bias-init + in-MFMAs, h_{ell-1}(t+1) written last
// tick by upstream), then GATES(t) from the acc finished this tick. Gates
// depend only on phase-B's chain; phase-A's independent MFMAs issue in between
// -> each wave's trans/VALU executes in the shadow of the in-flight MFMAs
// (sum -> max of the two pipes). Parity: reads (tau+1)&1, writes tau&1;
// intra-tick read/write LDS regions are disjoint -> no intra-tick race.
#define TICK(P0,P1,P2,P3, Q0,Q1,Q2,Q3, RD, WR, TAU)                            \
    {                                                                          \
        const int tB = (TAU) - 2 * ell;                                        \
        const bool actB = (unsigned)tB < (unsigned)SEQ;                        \
        const bool actA = (unsigned)(tB + 1) < (unsigned)SEQ;                  \
        if (actB) {   /* finish acc(t): self-MFMAs */                          \
            const f16x8 b2 = *(const f16x8*)(hb + (RD) + sfA0);                \
            const f16x8 b3 = *(const f16x8*)(hb + (RD) + sfA1);                \
            P0 = MFMA(wf[0][2], b2, P0);  P1 = MFMA(wf[1][2], b2, P1);         \
            P2 = MFMA(wf[2][2], b2, P2);  P3 = MFMA(wf[3][2], b2, P3);         \
            P0 = MFMA(wf[0][3], b3, P0);  P1 = MFMA(wf[1][3], b3, P1);         \
            P2 = MFMA(wf[2][3], b3, P2);  P3 = MFMA(wf[3][3], b3, P3);         \
        }                                                                      \
        if (actA) {   /* start acc(t+1): bias init + in-MFMAs */               \
            f16x8 b0, b1;                                                      \
            if (ell == 0) {                                                    \
                if (lam == 0) xf[0] = (_Float16)xrow[tB + 1];                  \
                b0 = xf; b1 = xf;      /* wf[i][1]==0 for ell 0 */             \
            } else {                                                           \
                b0 = *(const f16x8*)(hb + (RD) + inA0);                        \
                b1 = *(const f16x8*)(hb + (RD) + inA1);                        \
            }                                                                  \
            Q0 = *(const f32x4*)(bldsW + 0);                                   \
            Q1 = *(const f32x4*)(bldsW + 64);                                  \
            Q2 = *(const f32x4*)(bldsW + 128);                                 \
            Q3 = *(const f32x4*)(bldsW + 192);                                 \
            Q0 = MFMA(wf[0][0], b0, Q0);  Q1 = MFMA(wf[1][0], b0, Q1);         \
            Q2 = MFMA(wf[2][0], b0, Q2);  Q3 = MFMA(wf[3][0], b0, Q3);         \
            Q0 = MFMA(wf[0][1], b1, Q0);  Q1 = MFMA(wf[1][1], b1, Q1);         \
            Q2 = MFMA(wf[2][1], b1, Q2);  Q3 = MFMA(wf[3][1], b1, Q3);         \
        }                                                                      \
        if (actB) {   /* gates(t) from acc finished in phase B */              \
            const f32x4 s01 = k1b ? P1 : P0;                                   \
            const f32x4 s23 = k1b ? P3 : P2;                                   \
            const f32x4 aK  = k2b ? s23 : s01;                                 \
            const float gi = sig_(aK[0]);                                      \
            const float gf = sig_(aK[1]);                                      \
            const float gg = tanh_(aK[2]);                                     \
            const float go = sig_(aK[3]);                                      \
            cstK = fmaf(gf, cstK, gi * gg);                                    \
            const float hn = go * tanh_(cstK);                                 \
            *(_Float16*)(hb + (WR) + wrKS) = (_Float16)hn;                     \
            if (ell == 3) {                                                    \
                float v1 = hn, v2 = hn * hn, v3 = hn * gwK;                    \
                v1 += __shfl_xor(v1, 4, 64);  v2 += __shfl_xor(v2, 4, 64);  v3 += __shfl_xor(v3, 4, 64);  \
                v1 += __shfl_xor(v1, 8, 64);  v2 += __shfl_xor(v2, 8, 64);  v3 += __shfl_xor(v3, 8, 64);  \
                v1 += __shfl_xor(v1, 16, 64); v2 += __shfl_xor(v2, 16, 64); v3 += __shfl_xor(v3, 16, 64); \
                v1 += __shfl_xor(v1, 32, 64); v2 += __shfl_xor(v2, 32, 64); v3 += __shfl_xor(v3, 32, 64); \
                if (bc < 4) {                                                  \
                    float* pp = &part[tB & 15][om][bc][0];                     \
                    pp[0] = v1; pp[1] = v2; pp[2] = v3;                        \
                }                                                              \
            }                                                                  \
        }                                                                      \
        __syncthreads();                                                       \
        {                                                                      \
            const int t3 = (TAU) - 6;                                          \
            if (t3 >= 7 && (t3 & 7) == 7) {                                    \
                const int row = tid >> 4, sub = tid & 15;                      \
                if (row < 32) {                                                \
                    const int sl = row >> 2, b = row & 3;                      \
                    const int slot = (t3 - 7 + sl) & 15;                       \
                    float u1 = part[slot][sub & 3][b][0];                      \
                    float u2 = part[slot][sub & 3][b][1];                      \
                    float u3 = part[slot][sub & 3][b][2];                      \
                    u1 += __shfl_xor(u1, 1, 64); u2 += __shfl_xor(u2, 1, 64); u3 += __shfl_xor(u3, 1, 64); \
                    u1 += __shfl_xor(u1, 2, 64); u2 += __shfl_xor(u2, 2, 64); u3 += __shfl_xor(u3, 2, 64); \
                    if (sub == 0) {                                            \
                        const float mu = u1 * (1.0f / 64.0f);                  \
                        float var = fmaf(u2, 1.0f / 64.0f, -mu * mu);          \
                        var = fmaxf(var, 0.0f);                                \
                        const float rs = rsqrtf(var + 1e-5f);                  \
                        out[(bb * 4 + b) * SEQ + (t3 - 7) + sl] =              \
                            fmaf(rs, fmaf(-mu, Sgw, u3), Sbw);                 \
                    }                                                          \
                }                                                              \
            }                                                                  \
        }                                                                      \
    }

__global__ __launch_bounds__(NTHR, 4) void lstm4_swp(
    const float* __restrict__ x,
    const float* __restrict__ W0, const float* __restrict__ B0,
    const float* __restrict__ W1, const float* __restrict__ B1,
    const float* __restrict__ W2, const float* __restrict__ B2,
    const float* __restrict__ W3, const float* __restrict__ B3,
    const float* __restrict__ ln_g, const float* __restrict__ ln_b,
    const float* __restrict__ Wout, const float* __restrict__ bout,
    float* __restrict__ out)
{
    __shared__ __align__(16) _Float16 hbuf[2][4][4][64];   // 4 KB [parity][layer][b][k]
    __shared__ float xall[4][SEQ];                         // 8 KB
    __shared__ float part[16][4][4][3];                    // 3 KB
    __shared__ __align__(16) float blds[4][16][4][4];      // 4 KB biases [ell][T][lam][r]
    __shared__ float sconst[2];

    const int tid  = threadIdx.x;
    const int lane = tid & 63;
    const int w    = tid >> 6;        // wave 0..15
    const int ell  = w >> 2;          // layer
    const int om   = w & 3;           // tile quarter
    const int lam  = lane >> 4;
    const int bc   = lane & 15;
    const int br   = bc & 3;
    const int kq   = bc >> 2;         // owned tile within quarter
    const int bb   = blockIdx.x;

    // ---- stage x, zero h (both parities), biases -> LDS ----
    for (int i = tid; i < 4 * SEQ; i += NTHR)
        xall[i >> 9][i & 511] = x[bb * 4 * SEQ + i];
    for (int i = tid; i < 2 * 4 * 4 * 64; i += NTHR)
        ((_Float16*)hbuf)[i] = (_Float16)0.0f;
    {
        const int L = tid >> 8, idx = tid & 255;
        const int T = idx >> 4, lm = (idx >> 2) & 3, r = idx & 3;
        const float* Bp4 = (L == 0) ? B0 : (L == 1) ? B1 : (L == 2) ? B2 : B3;
        ((float*)blds)[tid] = Bp4[r * 64 + T * 4 + lm];
    }
    if (tid < 64) {
        float a = ln_g[tid] * Wout[tid];
        float b = ln_b[tid] * Wout[tid];
#pragma unroll
        for (int off = 32; off > 0; off >>= 1) {
            a += __shfl_xor(a, off, 64);
            b += __shfl_xor(b, off, 64);
        }
        if (tid == 0) { sconst[0] = a; sconst[1] = b; }
    }

    const float* Wp = (ell == 0) ? W0 : (ell == 1) ? W1 : (ell == 2) ? W2 : W3;

    // ---- weights: 4 tiles/wave, gate-permuted cols ----
    // wf[i][0..1] = in-frags (ell0: one-hot x + zero), wf[i][2..3] = self-frags
    f16x8 wf[4][4];
#pragma unroll
    for (int i = 0; i < 4; ++i) {
        const int T  = om * 4 + i;
        const int cA = (bc & 3) * 64 + T * 4 + (bc >> 2);
        if (ell == 0) {
#pragma unroll
            for (int kt = 0; kt < 2; ++kt)
#pragma unroll
                for (int e = 0; e < 8; ++e)
                    wf[i][2 + kt][e] = (_Float16)W0[(1 + kt * 32 + lam * 8 + e) * 256 + cA];
#pragma unroll
            for (int e = 0; e < 8; ++e) { wf[i][0][e] = (_Float16)0.0f; wf[i][1][e] = (_Float16)0.0f; }
            if (lam == 0) wf[i][0][0] = (_Float16)W0[cA];   // x weight, one-hot
        } else {
#pragma unroll
            for (int kt = 0; kt < 4; ++kt)        // 0,1 = in-h; 2,3 = self-h
#pragma unroll
                for (int e = 0; e < 8; ++e)
                    wf[i][kt][e] = (_Float16)Wp[(kt * 32 + lam * 8 + e) * 256 + cA];
        }
    }

    const int   mK  = (om * 4 + kq) * 4 + lam;
    const float gwK = ln_g[mK] * Wout[mK];
    const int   wrK = br * 128 + (((mK >> 3) ^ br) * 16) + (mK & 7) * 2;

    const int a0 = br * 128 + ((lam)     ^ br) * 16;
    const int a1 = br * 128 + ((4 + lam) ^ br) * 16;

    const int inA0 = (ell == 0) ? a0 : (ell - 1) * 512 + a0;
    const int inA1 = (ell == 0) ? a1 : (ell - 1) * 512 + a1;
    const int sfA0 = ell * 512 + a0;
    const int sfA1 = ell * 512 + a1;
    const int wrKS = ell * 512 + wrK;
    const char* const bldsW = (const char*)blds + ell * 1024 + om * 256 + lam * 16;
    const float* const xrow = &xall[br][0];

    const bool k1b = (bc & 4) != 0;
    const bool k2b = (bc & 8) != 0;

    f16x8 xf;
#pragma unroll
    for (int e = 0; e < 8; ++e) xf[e] = (_Float16)0.0f;

    float cstK = 0.0f;
    char* const hb = (char*)hbuf;

    f32x4 aA0, aA1, aA2, aA3;      // acc set A (P at even ticks)
    f32x4 aB0, aB1, aB2, aB3;      // acc set B (P at odd ticks)

    __syncthreads();
    const float Sgw = sconst[0];
    const float Sbw = sconst[1] + bout[0];

    // ---- pre-loop: layer-0 seeds acc(0) in set A (virtual tick -1 phase A) ----
    if (ell == 0) {
        if (lam == 0) xf[0] = (_Float16)xrow[0];
        const f16x8 b0 = xf;
        aA0 = *(const f32x4*)(bldsW + 0);
        aA1 = *(const f32x4*)(bldsW + 64);
        aA2 = *(const f32x4*)(bldsW + 128);
        aA3 = *(const f32x4*)(bldsW + 192);
        aA0 = MFMA(wf[0][0], b0, aA0);
        aA1 = MFMA(wf[1][0], b0, aA1);
        aA2 = MFMA(wf[2][0], b0, aA2);
        aA3 = MFMA(wf[3][0], b0, aA3);
    }

    // ---- main: 518 ticks = 259 unrolled pairs ----
    for (int j = 0; j < 259; ++j) {
        const int tau = 2 * j;
        // even tick: P = set A, Q = set B; reads parity 1 (2048), writes parity 0
        TICK(aA0, aA1, aA2, aA3, aB0, aB1, aB2, aB3, 2048, 0, tau)
        // odd tick: P = set B, Q = set A; reads parity 0, writes parity 1 (2048)
        TICK(aB0, aB1, aB2, aB3, aA0, aA1, aA2, aA3, 0, 2048, tau + 1)
    }
}

extern "C" void kernel_launch(void* const* d_in, const int* in_sizes, int n_in,
                              void* d_out, int out_size, void* d_ws, size_t ws_size,
                              hipStream_t stream)
{
    const float* x    = (const float*)d_in[0];
    const float* W0   = (const float*)d_in[1];
    const float* B0   = (const float*)d_in[2];
    const float* W1   = (const float*)d_in[3];
    const float* B1   = (const float*)d_in[4];
    const float* W2   = (const float*)d_in[5];
    const float* B2   = (const float*)d_in[6];
    const float* W3   = (const float*)d_in[7];
    const float* B3   = (const float*)d_in[8];
    const float* ln_g = (const float*)d_in[9];
    const float* ln_b = (const float*)d_in[10];
    const float* Wout = (const float*)d_in[11];
    const float* bout = (const float*)d_in[12];
    float* out = (float*)d_out;

    lstm4_swp<<<NBLK, NTHR, 0, stream>>>(x, W0, B0, W1, B1, W2, B2, W3, B3,
                                         ln_g, ln_b, Wout, bout, out);
}